// Round 5
// baseline (360.772 us; speedup 1.0000x reference)
//
#include <hip/hip_runtime.h>
#include <stdint.h>

#define F_IN 65536
#define NN 100
#define CO 60
#define G2 256              // split-K slices
#define KC (F_IN/G2)        // 256 k per slice
#define BK 64
#define NIT (KC/BK)         // 4
#define AST 72              // A LDS row stride in shorts (144 B: 16B-aligned, bank-rotating)
#define BTILE (BK*CO)       // 3840 shorts per B tile (one matrix)
#define BQ3 (3*BTILE/4)     // 2880 float4 per 3-matrix B stage
#define NBT 256             // tail blocks (1/CU guaranteed co-resident for grid barrier)

typedef short v8s __attribute__((ext_vector_type(8)));
typedef float v4f __attribute__((ext_vector_type(4)));

__device__ __forceinline__ unsigned int f2bf(float x){
  unsigned int u = __float_as_uint(x);
  u += 0x7fffu + ((u>>16)&1u);      // round-to-nearest-even
  return u>>16;
}

__device__ __forceinline__ v4f mfma16(v8s a, v8s b, v4f c){
  return __builtin_amdgcn_mfma_f32_16x16x32_bf16(a,b,c,0,0,0);
}

// ---------------------------------------------------------------------------
// K1: split-K GEMM — EXACT round-3 version (proven 47 us, 124 VGPR, no spill).
// 3 weight matrices per block (shared A tile = X).  grid = 512, 256 thr,
// lb(256,2).  Round-4's lb(512,4) variant spilled (VGPR cap 128 < ~170 need).
// ---------------------------------------------------------------------------
__global__ __launch_bounds__(256,2)
void k_gemm(const float* __restrict__ x, const float* __restrict__ aw,
            const float* __restrict__ cw, float* __restrict__ dst, int partial){
  const int bid  = blockIdx.x;
  const int xcd  = bid & 7, slot = bid >> 3;   // 64 slots/XCD
  const int net  = slot & 1;
  const int s    = xcd*32 + (slot >> 1);       // k-slice
  const int k0   = s*KC;
  const int tid  = threadIdx.x;
  const int wave = tid>>6, lane = tid&63, quad = lane>>4, nl = lane&15;
  const int c0   = wave*16;
  const int ccl  = min(c0+nl, CO-1);           // clamp pad cols; masked at store

  const float* Wn = net ? cw : aw;             // [3][F_IN][CO]

  __shared__ __align__(16) unsigned short Al[2][112*AST];   // 32.25 KB
  __shared__ __align__(16) unsigned short Bl[2][3*BTILE];   // 46.08 KB

  unsigned int boff[12];
  #pragma unroll
  for(int p=0;p<12;++p){
    int li = min(p*256 + tid, BQ3-1);
    int gp = li/960, fp = li - gp*960;
    boff[p] = (unsigned int)((size_t)gp*F_IN*CO + (size_t)fp*4)*4u;
  }
  const char* bbase0 = (const char*)(Wn + (size_t)k0*CO);

  float4 ra[7];
  float4 rbv[12];
  #pragma unroll
  for(int p=0;p<7;++p){
    int lin = p*256 + tid, row = lin>>4, q = lin&15;
    int rcl = min(row, NN-1);
    ra[p] = *(const float4*)(x + (size_t)rcl*F_IN + k0 + q*4);
  }
  #pragma unroll
  for(int p=0;p<12;++p) rbv[p] = *(const float4*)(bbase0 + boff[p]);

  v4f acc[3][7];
  #pragma unroll
  for(int g=0;g<3;++g)
    #pragma unroll
    for(int i=0;i<7;++i){ v4f z={0.f,0.f,0.f,0.f}; acc[g][i]=z; }

  for(int it=0; it<NIT; ++it){
    unsigned short* buf  = Al[it&1];
    unsigned short* bbuf = Bl[it&1];
    #pragma unroll
    for(int p=0;p<7;++p){
      int lin = p*256 + tid, row = lin>>4, q = lin&15;
      uint2 w;
      w.x = f2bf(ra[p].x) | (f2bf(ra[p].y)<<16);
      w.y = f2bf(ra[p].z) | (f2bf(ra[p].w)<<16);
      *(uint2*)(buf + row*AST + q*4) = w;
    }
    #pragma unroll
    for(int p=0;p<12;++p){
      int lin = p*256 + tid;
      if(lin < BQ3){
        uint2 w;
        w.x = f2bf(rbv[p].x) | (f2bf(rbv[p].y)<<16);
        w.y = f2bf(rbv[p].z) | (f2bf(rbv[p].w)<<16);
        *(uint2*)(bbuf + lin*4) = w;
      }
    }
    __syncthreads();
    if(it+1 < NIT){
      const int kb = k0 + (it+1)*BK;
      #pragma unroll
      for(int p=0;p<7;++p){
        int lin = p*256 + tid, row = lin>>4, q = lin&15;
        int rcl = min(row, NN-1);
        ra[p] = *(const float4*)(x + (size_t)rcl*F_IN + kb + q*4);
      }
      const char* bb2 = bbase0 + (size_t)(it+1)*BK*CO*4;
      #pragma unroll
      for(int p=0;p<12;++p) rbv[p] = *(const float4*)(bb2 + boff[p]);
    }
    v8s fB0[3], fB1[3];
    #pragma unroll
    for(int g=0;g<3;++g){
      const unsigned short* bb = bbuf + g*BTILE + quad*8*CO + ccl;
      #pragma unroll
      for(int j=0;j<8;++j){
        fB0[g][j] = (short)bb[j*CO];
        fB1[g][j] = (short)bb[32*CO + j*CO];
      }
    }
    #pragma unroll
    for(int mt=0; mt<7; ++mt){
      const unsigned short* arow = buf + (mt*16+nl)*AST + quad*8;
      v8s a0 = *(const v8s*)(arow);
      v8s a1 = *(const v8s*)(arow+32);
      #pragma unroll
      for(int g=0;g<3;++g){
        acc[g][mt] = mfma16(a0, fB0[g], acc[g][mt]);
        acc[g][mt] = mfma16(a1, fB1[g], acc[g][mt]);
      }
    }
  }

  const int c = c0 + nl;
  if(c < CO){
    #pragma unroll
    for(int g=0;g<3;++g){
      if(partial){
        float* pd = dst + ((size_t)(net*3+g)*G2 + s)*(NN*CO);
        #pragma unroll
        for(int mt=0;mt<7;++mt){
          #pragma unroll
          for(int i=0;i<4;++i){
            int m = mt*16 + quad*4 + i;
            if(m < NN) pd[m*CO + c] = acc[g][mt][i];
          }
        }
      } else {
        float* pd = dst + (size_t)(net*3+g)*(NN*CO);
        #pragma unroll
        for(int mt=0;mt<7;++mt){
          #pragma unroll
          for(int i=0;i<4;++i){
            int m = mt*16 + quad*4 + i;
            if(m < NN) atomicAdd(pd + m*CO + c, acc[g][mt][i]);
          }
        }
      }
    }
  }
}

// ---------------------------------------------------------------------------
// K2: fused tail, 256 blocks x 512 thr (1 block/CU -> co-resident; 8 waves/CU).
// Grid barrier: device-scope atomic counter + fences, s_sleep in spin.
// Phase 1: split-K reduce, 3 threads/output x ~86 slices (131K threads,
//          4-accum unrolled chains) + zero out[] (block 255).
// Phase 2: cheb combine (blocks 0..119, 512-thr strides).
// Phase 3: final FC (blocks 0..49 logits quarters, block 50 value+extras).
// ---------------------------------------------------------------------------
__device__ __forceinline__ void gridbar(unsigned* cnt, unsigned target){
  __syncthreads();
  __threadfence();
  if(threadIdx.x==0){
    __hip_atomic_fetch_add(cnt, 1u, __ATOMIC_ACQ_REL, __HIP_MEMORY_SCOPE_AGENT);
    while(__hip_atomic_load(cnt, __ATOMIC_ACQUIRE, __HIP_MEMORY_SCOPE_AGENT) < target)
      __builtin_amdgcn_s_sleep(4);
  }
  __syncthreads();
  __threadfence();
}

__global__ __launch_bounds__(512,1)
void k_tail2(const float* __restrict__ P, float* __restrict__ Y,
             const int* __restrict__ ei, const float* __restrict__ ab,
             const float* __restrict__ cb, const float* __restrict__ afw,
             const float* __restrict__ afb, const float* __restrict__ cfw,
             const float* __restrict__ cfb, const float* __restrict__ s0,
             const float* __restrict__ s1, const float* __restrict__ s2,
             float* __restrict__ emb, float* __restrict__ out,
             unsigned* __restrict__ bar, int partial){
  const int bid = blockIdx.x;
  const int t   = threadIdx.x;       // 512

  __shared__ float L[NN][NN+1];
  __shared__ float dis[NN];
  __shared__ int   deg[NN];
  __shared__ float y0[NN], y1[NN], y2[NN], zu[NN];
  __shared__ float red[8];

  // ---- phase 1: reduce P -> Y (Y pre-zeroed by memset; 3 parts/output) ----
  if(partial){
    int u = bid*512 + t;             // [0, 131072)
    if(u < 108000){
      int o    = u % 36000;          // consecutive u -> consecutive o: coalesced
      int part = u / 36000;          // 0..2
      int lo = part*86, hi = min(lo+86, G2);
      int gg = o/6000, r = o - gg*6000;
      const float* p = P + (size_t)gg*G2*6000 + r;
      float a0=0.f,a1=0.f,a2=0.f,a3=0.f;
      int i=lo;
      #pragma unroll 2
      for(; i+3<hi; i+=4){
        a0 += p[(size_t)(i  )*6000];
        a1 += p[(size_t)(i+1)*6000];
        a2 += p[(size_t)(i+2)*6000];
        a3 += p[(size_t)(i+3)*6000];
      }
      for(; i<hi; ++i) a0 += p[(size_t)i*6000];
      atomicAdd(&Y[o], (a0+a1)+(a2+a3));
    }
  }
  if(bid==255 && t<101) out[t] = 0.f;

  gridbar(bar, NBT);

  // ---- phase 2: cheb combine + tanh (blocks 0..119) ----
  if(bid < 120){
    const int net = bid / CO;
    const int c   = bid % CO;
    for(int i=t;i<NN*(NN+1);i+=512) ((float*)L)[i]=0.f;
    if(t<NN) deg[t]=0;
    __syncthreads();
    for(int e=t;e<2000;e+=512) atomicAdd(&deg[ei[e]],1);
    __syncthreads();
    if(t<NN) dis[t] = deg[t]>0 ? rsqrtf((float)deg[t]) : 0.f;
    __syncthreads();
    for(int e=t;e<2000;e+=512){
      int ss = ei[e], d = ei[2000+e];
      atomicAdd(&L[d][ss], -dis[ss]*dis[d]);
    }
    if(t<NN){
      const float* yb = Y + (size_t)net*3*NN*CO + t*CO + c;
      y0[t]=yb[0]; y1[t]=yb[NN*CO]; y2[t]=yb[2*NN*CO];
    }
    __syncthreads();
    if(t<NN){
      float sv=0.f;
      #pragma unroll 4
      for(int j=0;j<NN;++j) sv += L[t][j]*y2[j];
      zu[t] = y1[t] + 2.f*sv;
    }
    __syncthreads();
    if(t<NN){
      float sv=0.f;
      #pragma unroll 4
      for(int j=0;j<NN;++j) sv += L[t][j]*zu[j];
      float b = (net==0) ? ab[c] : cb[c];
      emb[net*NN*CO + t*CO + c] = tanhf(y0[t] - y2[t] + sv + b);
    }
  }

  gridbar(bar, 2*NBT);

  // ---- phase 3: final FC ----
  if(bid < 50){
    // logits partials: 120 emb rows/block, 4 quarters x 30 rows; lanes=out cols
    const int jj = t & 127, quarter = t >> 7;
    if(jj < 100){
      const int i0 = bid*120 + quarter*30;
      const float* w = afw + (size_t)i0*100 + jj;
      const float* e = emb + i0;
      float p0=0.f,p1=0.f;
      #pragma unroll 5
      for(int i=0;i<30;i+=2){
        p0 += e[i  ]*w[(size_t)(i  )*100];
        p1 += e[i+1]*w[(size_t)(i+1)*100];
      }
      atomicAdd(&out[jj], p0+p1);
    }
  } else if(bid == 50){
    float p = 0.f;
    const float* e = emb + 6000;
    for(int i=t;i<6000;i+=512) p += e[i]*cfw[i];
    #pragma unroll
    for(int o=32;o>0;o>>=1) p += __shfl_down(p,o,64);
    if((t&63)==0) red[t>>6]=p;
    __syncthreads();
    if(t==0){
      float tot = 0.f;
      #pragma unroll
      for(int i=0;i<8;++i) tot += red[i];
      out[100] = tot + s0[0]*cfw[6000] + s1[0]*cfw[6001] + s2[0]*cfw[6002] + cfb[0];
    }
    if(t<100){
      atomicAdd(&out[t], afb[t] + s0[0]*afw[600000+t] + s1[0]*afw[600100+t] + s2[0]*afw[600200+t]);
    }
  }
}

extern "C" void kernel_launch(void* const* d_in, const int* in_sizes, int n_in,
                              void* d_out, int out_size, void* d_ws, size_t ws_size,
                              hipStream_t stream){
  const float* x   = (const float*)d_in[0];
  const int*   ei  = (const int*)d_in[1];
  const float* s0  = (const float*)d_in[2];
  const float* s1  = (const float*)d_in[3];
  const float* s2  = (const float*)d_in[4];
  const float* aw  = (const float*)d_in[5];
  const float* ab  = (const float*)d_in[6];
  const float* cw  = (const float*)d_in[7];
  const float* cb  = (const float*)d_in[8];
  const float* afw = (const float*)d_in[9];
  const float* afb = (const float*)d_in[10];
  const float* cfw = (const float*)d_in[11];
  const float* cfb = (const float*)d_in[12];
  float* out = (float*)d_out;

  float*    Y   = (float*)d_ws;                  // [6][6000]
  unsigned* bar = (unsigned*)(Y + 6*NN*CO);      // [16] barrier counter
  float*    emb = (float*)(bar + 16);            // [2][6000]
  float*    P   = emb + 2*NN*CO;                 // [6][G2][6000] split-K partials
  const size_t need = (size_t)(6*NN*CO + 16 + 2*NN*CO)*4 + (size_t)6*G2*NN*CO*4;
  const int partial = (ws_size >= need) ? 1 : 0;

  // zero Y + bar in one memset (contiguous)
  hipMemsetAsync(Y, 0, 6*NN*CO*sizeof(float) + 16*sizeof(unsigned), stream);

  k_gemm<<<dim3(512), 256, 0, stream>>>(x, aw, cw, partial ? P : Y, partial);
  k_tail2<<<dim3(NBT), 512, 0, stream>>>(P, Y, ei, ab, cb, afw, afb, cfw, cfb,
                                         s0, s1, s2, emb, out, bar, partial);
}

// Round 6
// 244.135 us; speedup vs baseline: 1.4778x; 1.4778x over previous
//
#include <hip/hip_runtime.h>
#include <stdint.h>

#define F_IN 65536
#define NN 100
#define CO 60
#define G2 256              // split-K slices
#define KC (F_IN/G2)        // 256 k per slice
#define BK 64
#define NIT (KC/BK)         // 4
#define AST 72              // A LDS row stride in shorts (144 B: 16B-aligned, bank-rotating)
#define BTILE (BK*CO)       // 3840 shorts per B tile (one matrix)
#define BQ3 (3*BTILE/4)     // 2880 float4 per 3-matrix B stage

typedef short v8s __attribute__((ext_vector_type(8)));
typedef float v4f __attribute__((ext_vector_type(4)));

__device__ __forceinline__ unsigned int f2bf(float x){
  unsigned int u = __float_as_uint(x);
  u += 0x7fffu + ((u>>16)&1u);      // round-to-nearest-even
  return u>>16;
}

__device__ __forceinline__ v4f mfma16(v8s a, v8s b, v4f c){
  return __builtin_amdgcn_mfma_f32_16x16x32_bf16(a,b,c,0,0,0);
}

// ---------------------------------------------------------------------------
// K1: split-K GEMM — round-3 core (proven 47 us, 124 VGPR, no spill), but the
// epilogue atomicAdds straight into Y[6][6000] (no partial slab, no reduce
// kernel).  Eliminates 37 MB write + 37 MB strided re-read + 1 dispatch.
// Atomics: 240 thr x 84 adds x 512 blocks = 9.2M device-scope f32 adds,
// 256 contenders/address spread over the kernel's lifetime.
// ---------------------------------------------------------------------------
__global__ __launch_bounds__(256,2)
void k_gemm(const float* __restrict__ x, const float* __restrict__ aw,
            const float* __restrict__ cw, float* __restrict__ Y){
  const int bid  = blockIdx.x;
  const int xcd  = bid & 7, slot = bid >> 3;   // 64 slots/XCD
  const int net  = slot & 1;
  const int s    = xcd*32 + (slot >> 1);       // k-slice
  const int k0   = s*KC;
  const int tid  = threadIdx.x;
  const int wave = tid>>6, lane = tid&63, quad = lane>>4, nl = lane&15;
  const int c0   = wave*16;
  const int ccl  = min(c0+nl, CO-1);           // clamp pad cols; masked at store

  const float* Wn = net ? cw : aw;             // [3][F_IN][CO]

  __shared__ __align__(16) unsigned short Al[2][112*AST];   // 32.25 KB
  __shared__ __align__(16) unsigned short Bl[2][3*BTILE];   // 46.08 KB

  unsigned int boff[12];
  #pragma unroll
  for(int p=0;p<12;++p){
    int li = min(p*256 + tid, BQ3-1);
    int gp = li/960, fp = li - gp*960;
    boff[p] = (unsigned int)((size_t)gp*F_IN*CO + (size_t)fp*4)*4u;
  }
  const char* bbase0 = (const char*)(Wn + (size_t)k0*CO);

  float4 ra[7];
  float4 rbv[12];
  #pragma unroll
  for(int p=0;p<7;++p){
    int lin = p*256 + tid, row = lin>>4, q = lin&15;
    int rcl = min(row, NN-1);
    ra[p] = *(const float4*)(x + (size_t)rcl*F_IN + k0 + q*4);
  }
  #pragma unroll
  for(int p=0;p<12;++p) rbv[p] = *(const float4*)(bbase0 + boff[p]);

  v4f acc[3][7];
  #pragma unroll
  for(int g=0;g<3;++g)
    #pragma unroll
    for(int i=0;i<7;++i){ v4f z={0.f,0.f,0.f,0.f}; acc[g][i]=z; }

  for(int it=0; it<NIT; ++it){
    unsigned short* buf  = Al[it&1];
    unsigned short* bbuf = Bl[it&1];
    #pragma unroll
    for(int p=0;p<7;++p){
      int lin = p*256 + tid, row = lin>>4, q = lin&15;
      uint2 w;
      w.x = f2bf(ra[p].x) | (f2bf(ra[p].y)<<16);
      w.y = f2bf(ra[p].z) | (f2bf(ra[p].w)<<16);
      *(uint2*)(buf + row*AST + q*4) = w;
    }
    #pragma unroll
    for(int p=0;p<12;++p){
      int lin = p*256 + tid;
      if(lin < BQ3){
        uint2 w;
        w.x = f2bf(rbv[p].x) | (f2bf(rbv[p].y)<<16);
        w.y = f2bf(rbv[p].z) | (f2bf(rbv[p].w)<<16);
        *(uint2*)(bbuf + lin*4) = w;
      }
    }
    __syncthreads();
    if(it+1 < NIT){
      const int kb = k0 + (it+1)*BK;
      #pragma unroll
      for(int p=0;p<7;++p){
        int lin = p*256 + tid, row = lin>>4, q = lin&15;
        int rcl = min(row, NN-1);
        ra[p] = *(const float4*)(x + (size_t)rcl*F_IN + kb + q*4);
      }
      const char* bb2 = bbase0 + (size_t)(it+1)*BK*CO*4;
      #pragma unroll
      for(int p=0;p<12;++p) rbv[p] = *(const float4*)(bb2 + boff[p]);
    }
    v8s fB0[3], fB1[3];
    #pragma unroll
    for(int g=0;g<3;++g){
      const unsigned short* bb = bbuf + g*BTILE + quad*8*CO + ccl;
      #pragma unroll
      for(int j=0;j<8;++j){
        fB0[g][j] = (short)bb[j*CO];
        fB1[g][j] = (short)bb[32*CO + j*CO];
      }
    }
    #pragma unroll
    for(int mt=0; mt<7; ++mt){
      const unsigned short* arow = buf + (mt*16+nl)*AST + quad*8;
      v8s a0 = *(const v8s*)(arow);
      v8s a1 = *(const v8s*)(arow+32);
      #pragma unroll
      for(int g=0;g<3;++g){
        acc[g][mt] = mfma16(a0, fB0[g], acc[g][mt]);
        acc[g][mt] = mfma16(a1, fB1[g], acc[g][mt]);
      }
    }
  }

  // --- epilogue: direct device atomics into Y.  C/D: col=lane&15, row=quad*4+i
  const int c = c0 + nl;
  if(c < CO){
    #pragma unroll
    for(int g=0;g<3;++g){
      float* pd = Y + (size_t)(net*3+g)*(NN*CO);
      #pragma unroll
      for(int mt=0;mt<7;++mt){
        #pragma unroll
        for(int i=0;i<4;++i){
          int m = mt*16 + quad*4 + i;
          if(m < NN) atomicAdd(pd + m*CO + c, acc[g][mt][i]);
        }
      }
    }
  }
}

// ---------------------------------------------------------------------------
// K2: cheb combine.  out = Y0 - Y2 + L@(Y1 + 2*L@Y2) + b, then tanh.
// One block per (net, output column c).  L (100x100) rebuilt in LDS per block.
// Block 0 also zeroes out[0..100] (k_fc runs stream-later).
// ---------------------------------------------------------------------------
__global__ void k_cheb(const float* __restrict__ Y, const int* __restrict__ ei,
                       const float* __restrict__ ab, const float* __restrict__ cb,
                       float* __restrict__ emb, float* __restrict__ out){
  const int net = blockIdx.x / CO;
  const int c   = blockIdx.x % CO;
  const int t   = threadIdx.x;       // 128
  __shared__ float L[NN][NN+1];      // stride 101: 2-way bank alias only
  __shared__ float dis[NN];
  __shared__ int   deg[NN];
  __shared__ float y0[NN], y1[NN], y2[NN], zu[NN];

  if(blockIdx.x==0 && t<101) out[t] = 0.f;

  for(int i=t;i<NN*(NN+1);i+=128) ((float*)L)[i]=0.f;
  if(t<NN) deg[t]=0;
  __syncthreads();
  for(int e=t;e<2000;e+=128) atomicAdd(&deg[ei[e]],1);
  __syncthreads();
  if(t<NN) dis[t] = deg[t]>0 ? rsqrtf((float)deg[t]) : 0.f;
  __syncthreads();
  for(int e=t;e<2000;e+=128){
    int ss = ei[e], d = ei[2000+e];
    atomicAdd(&L[d][ss], -dis[ss]*dis[d]);
  }
  if(t<NN){
    const float* yb = Y + (size_t)net*3*NN*CO + t*CO + c;
    y0[t]=yb[0]; y1[t]=yb[NN*CO]; y2[t]=yb[2*NN*CO];
  }
  __syncthreads();
  if(t<NN){
    float sv=0.f;
    #pragma unroll 4
    for(int j=0;j<NN;++j) sv += L[t][j]*y2[j];
    zu[t] = y1[t] + 2.f*sv;
  }
  __syncthreads();
  if(t<NN){
    float sv=0.f;
    #pragma unroll 4
    for(int j=0;j<NN;++j) sv += L[t][j]*zu[j];
    float b = (net==0) ? ab[c] : cb[c];
    emb[net*NN*CO + t*CO + c] = tanhf(y0[t] - y2[t] + sv + b);
  }
}

// ---------------------------------------------------------------------------
// K3: final FC.  out zeroed by k_cheb block 0.  Blocks 0..49: logits partials
// (lane = output column j, 120 i-rows per block, 4 independent accumulators),
// atomicAdd.  Block 50: value dot + biases + scalar extras.
// ---------------------------------------------------------------------------
#define FCB 50
__global__ void k_fc(const float* __restrict__ emb, const float* __restrict__ afw,
                     const float* __restrict__ afb, const float* __restrict__ cfw,
                     const float* __restrict__ cfb, const float* __restrict__ s0,
                     const float* __restrict__ s1, const float* __restrict__ s2,
                     float* __restrict__ out){
  const int b = blockIdx.x;
  const int t = threadIdx.x;         // 256
  if(b < FCB){
    const int jj = t & 127, half = t >> 7;
    if(jj < 100){
      const int i0 = b*120 + half*60;
      const float* w = afw + (size_t)i0*100 + jj;
      const float* e = emb + i0;
      float p0=0.f,p1=0.f,p2=0.f,p3=0.f;
      #pragma unroll 3
      for(int i=0;i<60;i+=4){
        p0 += e[i  ]*w[(size_t)(i  )*100];
        p1 += e[i+1]*w[(size_t)(i+1)*100];
        p2 += e[i+2]*w[(size_t)(i+2)*100];
        p3 += e[i+3]*w[(size_t)(i+3)*100];
      }
      atomicAdd(&out[jj], (p0+p1)+(p2+p3));
    }
  } else {
    float p = 0.f;
    const float* e = emb + 6000;
    for(int i=t;i<6000;i+=256) p += e[i]*cfw[i];
    #pragma unroll
    for(int o=32;o>0;o>>=1) p += __shfl_down(p,o,64);
    __shared__ float red[4];
    if((t&63)==0) red[t>>6]=p;
    __syncthreads();
    if(t==0){
      float tot = red[0]+red[1]+red[2]+red[3];
      out[100] = tot + s0[0]*cfw[6000] + s1[0]*cfw[6001] + s2[0]*cfw[6002] + cfb[0];
    }
    if(t<100){
      atomicAdd(&out[t], afb[t] + s0[0]*afw[600000+t] + s1[0]*afw[600100+t] + s2[0]*afw[600200+t]);
    }
  }
}

extern "C" void kernel_launch(void* const* d_in, const int* in_sizes, int n_in,
                              void* d_out, int out_size, void* d_ws, size_t ws_size,
                              hipStream_t stream){
  const float* x   = (const float*)d_in[0];
  const int*   ei  = (const int*)d_in[1];
  const float* s0  = (const float*)d_in[2];
  const float* s1  = (const float*)d_in[3];
  const float* s2  = (const float*)d_in[4];
  const float* aw  = (const float*)d_in[5];
  const float* ab  = (const float*)d_in[6];
  const float* cw  = (const float*)d_in[7];
  const float* cb  = (const float*)d_in[8];
  const float* afw = (const float*)d_in[9];
  const float* afb = (const float*)d_in[10];
  const float* cfw = (const float*)d_in[11];
  const float* cfb = (const float*)d_in[12];
  float* out = (float*)d_out;

  float* Y   = (float*)d_ws;                     // [6][6000] accumulated GEMM outputs
  float* emb = Y + 6*NN*CO;                      // [2][6000] tanh embeddings

  hipMemsetAsync(Y, 0, 6*NN*CO*sizeof(float), stream);

  k_gemm<<<dim3(512), 256, 0, stream>>>(x, aw, cw, Y);
  k_cheb<<<120, 128, 0, stream>>>(Y, ei, ab, cb, emb, out);
  k_fc<<<FCB+1, 256, 0, stream>>>(emb, afw, afb, cfw, cfb, s0, s1, s2, out);
}

// Round 7
// 238.603 us; speedup vs baseline: 1.5120x; 1.0232x over previous
//
#include <hip/hip_runtime.h>
#include <stdint.h>

#define F_IN 65536
#define NN 100
#define CO 60
#define G2 256              // split-K slices
#define KC (F_IN/G2)        // 256 k per slice
#define BK 64
#define NIT (KC/BK)         // 4
#define AST 72              // A LDS row stride in shorts (144 B: 16B-aligned, bank-rotating)
#define BTILE (BK*CO)       // 3840 shorts per B tile (one matrix)
#define BQ3 (3*BTILE/4)     // 2880 float4 per 3-matrix B stage

typedef short v8s __attribute__((ext_vector_type(8)));
typedef float v4f __attribute__((ext_vector_type(4)));

__device__ __forceinline__ unsigned int f2bf(float x){
  unsigned int u = __float_as_uint(x);
  u += 0x7fffu + ((u>>16)&1u);      // round-to-nearest-even
  return u>>16;
}

__device__ __forceinline__ v4f mfma16(v8s a, v8s b, v4f c){
  return __builtin_amdgcn_mfma_f32_16x16x32_bf16(a,b,c,0,0,0);
}

// ---------------------------------------------------------------------------
// K1: split-K GEMM, 3 weight matrices per block (round-3 core) + PINNED
// prefetch: __builtin_amdgcn_sched_barrier(0) after the load-issue block
// prevents the compiler from sinking the next-tile loads down to their
// LDS-write use (which it provably did: 124 VGPR < acc 84 + prefetch 76 +
// addressing).  Loads now stay in flight behind the MFMA phase.
// VGPR expected ~180-230, still <=256 -> occupancy unchanged (8 waves/CU).
// ---------------------------------------------------------------------------
__global__ __launch_bounds__(256,2)
void k_gemm(const float* __restrict__ x, const float* __restrict__ aw,
            const float* __restrict__ cw, float* __restrict__ dst, int partial){
  const int bid  = blockIdx.x;
  const int xcd  = bid & 7, slot = bid >> 3;   // 64 slots/XCD
  const int net  = slot & 1;
  const int s    = xcd*32 + (slot >> 1);       // k-slice
  const int k0   = s*KC;
  const int tid  = threadIdx.x;
  const int wave = tid>>6, lane = tid&63, quad = lane>>4, nl = lane&15;
  const int c0   = wave*16;
  const int ccl  = min(c0+nl, CO-1);           // clamp pad cols; masked at store

  const float* Wn = net ? cw : aw;             // [3][F_IN][CO]

  __shared__ __align__(16) unsigned short Al[2][112*AST];   // 32.25 KB
  __shared__ __align__(16) unsigned short Bl[2][3*BTILE];   // 46.08 KB

  unsigned int boff[12];
  #pragma unroll
  for(int p=0;p<12;++p){
    int li = min(p*256 + tid, BQ3-1);
    int gp = li/960, fp = li - gp*960;
    boff[p] = (unsigned int)((size_t)gp*F_IN*CO + (size_t)fp*4)*4u;
  }
  const char* bbase0 = (const char*)(Wn + (size_t)k0*CO);

  float4 ra[7];
  float4 rbv[12];
  #pragma unroll
  for(int p=0;p<7;++p){
    int lin = p*256 + tid, row = lin>>4, q = lin&15;
    int rcl = min(row, NN-1);
    ra[p] = *(const float4*)(x + (size_t)rcl*F_IN + k0 + q*4);
  }
  #pragma unroll
  for(int p=0;p<12;++p) rbv[p] = *(const float4*)(bbase0 + boff[p]);

  v4f acc[3][7];
  #pragma unroll
  for(int g=0;g<3;++g)
    #pragma unroll
    for(int i=0;i<7;++i){ v4f z={0.f,0.f,0.f,0.f}; acc[g][i]=z; }

  for(int it=0; it<NIT; ++it){
    unsigned short* buf  = Al[it&1];
    unsigned short* bbuf = Bl[it&1];
    // --- write prefetched A tile (bf16) ---
    #pragma unroll
    for(int p=0;p<7;++p){
      int lin = p*256 + tid, row = lin>>4, q = lin&15;
      uint2 w;
      w.x = f2bf(ra[p].x) | (f2bf(ra[p].y)<<16);
      w.y = f2bf(ra[p].z) | (f2bf(ra[p].w)<<16);
      *(uint2*)(buf + row*AST + q*4) = w;
    }
    // --- write prefetched B tiles (bf16, flat [3][64][60]) ---
    #pragma unroll
    for(int p=0;p<12;++p){
      int lin = p*256 + tid;
      if(lin < BQ3){
        uint2 w;
        w.x = f2bf(rbv[p].x) | (f2bf(rbv[p].y)<<16);
        w.y = f2bf(rbv[p].z) | (f2bf(rbv[p].w)<<16);
        *(uint2*)(bbuf + lin*4) = w;
      }
    }
    __syncthreads();
    // --- kick next iteration's global loads, then PIN them here ---
    if(it+1 < NIT){
      const int kb = k0 + (it+1)*BK;
      #pragma unroll
      for(int p=0;p<7;++p){
        int lin = p*256 + tid, row = lin>>4, q = lin&15;
        int rcl = min(row, NN-1);
        ra[p] = *(const float4*)(x + (size_t)rcl*F_IN + kb + q*4);
      }
      const char* bb2 = bbase0 + (size_t)(it+1)*BK*CO*4;
      #pragma unroll
      for(int p=0;p<12;++p) rbv[p] = *(const float4*)(bb2 + boff[p]);
    }
    // Fence: loads above may not sink below; compute below may not hoist above.
    __builtin_amdgcn_sched_barrier(0);
    // --- B fragments from LDS (3 g x 16 ds_read_u16, stride 60 shorts) ---
    v8s fB0[3], fB1[3];
    #pragma unroll
    for(int g=0;g<3;++g){
      const unsigned short* bb = bbuf + g*BTILE + quad*8*CO + ccl;
      #pragma unroll
      for(int j=0;j<8;++j){
        fB0[g][j] = (short)bb[j*CO];
        fB1[g][j] = (short)bb[32*CO + j*CO];
      }
    }
    // --- MFMA: A frag read once, used by all 3 matrices ---
    #pragma unroll
    for(int mt=0; mt<7; ++mt){
      const unsigned short* arow = buf + (mt*16+nl)*AST + quad*8;
      v8s a0 = *(const v8s*)(arow);
      v8s a1 = *(const v8s*)(arow+32);
      #pragma unroll
      for(int g=0;g<3;++g){
        acc[g][mt] = mfma16(a0, fB0[g], acc[g][mt]);
        acc[g][mt] = mfma16(a1, fB1[g], acc[g][mt]);
      }
    }
  }

  // --- epilogue.  C/D layout: col=lane&15, row=quad*4+i ---
  const int c = c0 + nl;
  if(c < CO){
    #pragma unroll
    for(int g=0;g<3;++g){
      if(partial){
        float* pd = dst + ((size_t)(net*3+g)*G2 + s)*(NN*CO);
        #pragma unroll
        for(int mt=0;mt<7;++mt){
          #pragma unroll
          for(int i=0;i<4;++i){
            int m = mt*16 + quad*4 + i;
            if(m < NN) pd[m*CO + c] = acc[g][mt][i];
          }
        }
      } else {
        float* pd = dst + (size_t)(net*3+g)*(NN*CO);
        #pragma unroll
        for(int mt=0;mt<7;++mt){
          #pragma unroll
          for(int i=0;i<4;++i){
            int m = mt*16 + quad*4 + i;
            if(m < NN) atomicAdd(pd + m*CO + c, acc[g][mt][i]);
          }
        }
      }
    }
  }
}

// ---------------------------------------------------------------------------
// K1b: split-K reduce.  grid=(141,16): block (b,sg) sums 16 slices of P into Y
// via one atomicAdd (Y zeroed by memset).  16-load chains (4 accumulators)
// halve the latency rounds vs round-3's 32-slice version.
// ---------------------------------------------------------------------------
__global__ void k_reduce(const float* __restrict__ P, float* __restrict__ Y){
  int o = blockIdx.x*256 + threadIdx.x;
  if(o >= 6*NN*CO) return;
  int gg = o/(NN*CO), r = o - gg*(NN*CO);
  const float* p = P + (size_t)gg*G2*(NN*CO) + (size_t)blockIdx.y*16*(NN*CO) + r;
  float a0=0.f,a1=0.f,a2=0.f,a3=0.f;
  #pragma unroll
  for(int s4=0;s4<16;s4+=4){
    a0 += p[(size_t)(s4  )*(NN*CO)];
    a1 += p[(size_t)(s4+1)*(NN*CO)];
    a2 += p[(size_t)(s4+2)*(NN*CO)];
    a3 += p[(size_t)(s4+3)*(NN*CO)];
  }
  atomicAdd(&Y[o], (a0+a1)+(a2+a3));
}

// ---------------------------------------------------------------------------
// K2: cheb combine.  out = Y0 - Y2 + L@(Y1 + 2*L@Y2) + b, then tanh.
// One block per (net, output column c).  L (100x100) rebuilt in LDS per block.
// Block 0 also zeroes out[0..100].
// ---------------------------------------------------------------------------
__global__ void k_cheb(const float* __restrict__ Y, const int* __restrict__ ei,
                       const float* __restrict__ ab, const float* __restrict__ cb,
                       float* __restrict__ emb, float* __restrict__ out){
  const int net = blockIdx.x / CO;
  const int c   = blockIdx.x % CO;
  const int t   = threadIdx.x;       // 128
  __shared__ float L[NN][NN+1];      // stride 101: 2-way bank alias only
  __shared__ float dis[NN];
  __shared__ int   deg[NN];
  __shared__ float y0[NN], y1[NN], y2[NN], zu[NN];

  if(blockIdx.x==0 && t<101) out[t] = 0.f;

  for(int i=t;i<NN*(NN+1);i+=128) ((float*)L)[i]=0.f;
  if(t<NN) deg[t]=0;
  __syncthreads();
  for(int e=t;e<2000;e+=128) atomicAdd(&deg[ei[e]],1);
  __syncthreads();
  if(t<NN) dis[t] = deg[t]>0 ? rsqrtf((float)deg[t]) : 0.f;
  __syncthreads();
  for(int e=t;e<2000;e+=128){
    int ss = ei[e], d = ei[2000+e];
    atomicAdd(&L[d][ss], -dis[ss]*dis[d]);
  }
  if(t<NN){
    const float* yb = Y + (size_t)net*3*NN*CO + t*CO + c;
    y0[t]=yb[0]; y1[t]=yb[NN*CO]; y2[t]=yb[2*NN*CO];
  }
  __syncthreads();
  if(t<NN){
    float sv=0.f;
    #pragma unroll 4
    for(int j=0;j<NN;++j) sv += L[t][j]*y2[j];
    zu[t] = y1[t] + 2.f*sv;
  }
  __syncthreads();
  if(t<NN){
    float sv=0.f;
    #pragma unroll 4
    for(int j=0;j<NN;++j) sv += L[t][j]*zu[j];
    float b = (net==0) ? ab[c] : cb[c];
    emb[net*NN*CO + t*CO + c] = tanhf(y0[t] - y2[t] + sv + b);
  }
}

// ---------------------------------------------------------------------------
// K3: final FC.  out zeroed by k_cheb block 0.  Blocks 0..49: logits partials
// (lane = output column j, 120 i-rows per block, 4 independent accumulators),
// atomicAdd.  Block 50: value dot + biases + scalar extras.
// ---------------------------------------------------------------------------
#define FCB 50
__global__ void k_fc(const float* __restrict__ emb, const float* __restrict__ afw,
                     const float* __restrict__ afb, const float* __restrict__ cfw,
                     const float* __restrict__ cfb, const float* __restrict__ s0,
                     const float* __restrict__ s1, const float* __restrict__ s2,
                     float* __restrict__ out){
  const int b = blockIdx.x;
  const int t = threadIdx.x;         // 256
  if(b < FCB){
    const int jj = t & 127, half = t >> 7;
    if(jj < 100){
      const int i0 = b*120 + half*60;
      const float* w = afw + (size_t)i0*100 + jj;
      const float* e = emb + i0;
      float p0=0.f,p1=0.f,p2=0.f,p3=0.f;
      #pragma unroll 3
      for(int i=0;i<60;i+=4){
        p0 += e[i  ]*w[(size_t)(i  )*100];
        p1 += e[i+1]*w[(size_t)(i+1)*100];
        p2 += e[i+2]*w[(size_t)(i+2)*100];
        p3 += e[i+3]*w[(size_t)(i+3)*100];
      }
      atomicAdd(&out[jj], (p0+p1)+(p2+p3));
    }
  } else {
    float p = 0.f;
    const float* e = emb + 6000;
    for(int i=t;i<6000;i+=256) p += e[i]*cfw[i];
    #pragma unroll
    for(int o=32;o>0;o>>=1) p += __shfl_down(p,o,64);
    __shared__ float red[4];
    if((t&63)==0) red[t>>6]=p;
    __syncthreads();
    if(t==0){
      float tot = red[0]+red[1]+red[2]+red[3];
      out[100] = tot + s0[0]*cfw[6000] + s1[0]*cfw[6001] + s2[0]*cfw[6002] + cfb[0];
    }
    if(t<100){
      atomicAdd(&out[t], afb[t] + s0[0]*afw[600000+t] + s1[0]*afw[600100+t] + s2[0]*afw[600200+t]);
    }
  }
}

extern "C" void kernel_launch(void* const* d_in, const int* in_sizes, int n_in,
                              void* d_out, int out_size, void* d_ws, size_t ws_size,
                              hipStream_t stream){
  const float* x   = (const float*)d_in[0];
  const int*   ei  = (const int*)d_in[1];
  const float* s0  = (const float*)d_in[2];
  const float* s1  = (const float*)d_in[3];
  const float* s2  = (const float*)d_in[4];
  const float* aw  = (const float*)d_in[5];
  const float* ab  = (const float*)d_in[6];
  const float* cw  = (const float*)d_in[7];
  const float* cb  = (const float*)d_in[8];
  const float* afw = (const float*)d_in[9];
  const float* afb = (const float*)d_in[10];
  const float* cfw = (const float*)d_in[11];
  const float* cfb = (const float*)d_in[12];
  float* out = (float*)d_out;

  float* Y   = (float*)d_ws;                       // [6][6000] reduced GEMM outputs
  float* emb = Y + 6*NN*CO;                        // [2][6000] tanh embeddings
  float* P   = emb + 2*NN*CO;                      // [6][G2][6000] split-K partials
  const size_t need = (size_t)(6*NN*CO + 2*NN*CO)*4 + (size_t)6*G2*NN*CO*4;
  const int partial = (ws_size >= need) ? 1 : 0;

  hipMemsetAsync(Y, 0, 6*NN*CO*sizeof(float), stream);

  if(partial){
    k_gemm<<<dim3(512), 256, 0, stream>>>(x, aw, cw, P, 1);
    k_reduce<<<dim3((6*NN*CO+255)/256, 16), 256, 0, stream>>>(P, Y);
  } else {
    k_gemm<<<dim3(512), 256, 0, stream>>>(x, aw, cw, Y, 0);
  }
  k_cheb<<<120, 128, 0, stream>>>(Y, ei, ab, cb, emb, out);
  k_fc<<<FCB+1, 256, 0, stream>>>(emb, afw, afb, cfw, cfb, s0, s1, s2, out);
}

// Round 9
// 209.925 us; speedup vs baseline: 1.7186x; 1.1366x over previous
//
#include <hip/hip_runtime.h>
#include <stdint.h>

#define F_IN 65536
#define NN 100
#define CO 60
#define G2 256              // split-K slices
#define KC (F_IN/G2)        // 256 k per slice
#define BK 32
#define NIT (KC/BK)         // 8
// LDS (f32, per buffer): A 114-row region, row stride 36 floats (144 B: bank-
// rotating, 16B-multiple so each 16B staging window sits in one row); 16
// windows/inst x 16 insts = 4096 floats.  B: 3 x [32][60] linear = 5760 floats.
#define ABUF 4096
#define BBUF 5760

typedef short v8s __attribute__((ext_vector_type(8)));
typedef float v4f __attribute__((ext_vector_type(4)));

union U8 { unsigned u[4]; v8s s; };

__device__ __forceinline__ void cvtpk(unsigned &d, float a, float b){
  asm("v_cvt_pk_bf16_f32 %0, %1, %2" : "=v"(d) : "v"(a), "v"(b));
}

__device__ __forceinline__ v4f mfma16(v8s a, v8s b, v4f c){
  return __builtin_amdgcn_mfma_f32_16x16x32_bf16(a,b,c,0,0,0);
}

typedef const __attribute__((address_space(1))) unsigned int* gp_t;
typedef __attribute__((address_space(3))) unsigned int* lp_t;

__device__ __forceinline__ void gl16(const float* src, float* dst){
  __builtin_amdgcn_global_load_lds((gp_t)src, (lp_t)dst, 16, 0, 0);
}
__device__ __forceinline__ void gl4(const float* src, float* dst){
  __builtin_amdgcn_global_load_lds((gp_t)src, (lp_t)dst, 4, 0, 0);
}

// ---------------------------------------------------------------------------
// K1: split-K GEMM, 3 weight matrices per block; staging via global_load_lds
// (f32 in LDS; in-flight state lives in the vmcnt queue, NOT VGPRs — fixes
// r6/r7's failed register pipeline without spills).  2-phase pipeline:
// STAGE(next buf) -> compute(cur) -> vmcnt(0) -> barrier.  bf16 conversion
// moved to fragment-read path (v_cvt_pk_bf16_f32, 1 op / 2 values).
// A staged per-lane-source -> linear LDS windows (row = w16/9, 144-B rows);
// B staged as straight linear copies (7x16B + 2x4B insts per matrix).
// ---------------------------------------------------------------------------
__global__ __launch_bounds__(256,2)
void k_gemm(const float* __restrict__ x, const float* __restrict__ aw,
            const float* __restrict__ cw, float* __restrict__ dst, int partial){
  const int bid  = blockIdx.x;
  const int xcd  = bid & 7, slot = bid >> 3;   // 64 slots/XCD
  const int net  = slot & 1;
  const int s    = xcd*32 + (slot >> 1);       // k-slice
  const int k0   = s*KC;
  const int tid  = threadIdx.x;
  const int wave = tid>>6, lane = tid&63, quad = lane>>4, nl = lane&15;
  const int c0   = wave*16;
  const int ccl  = min(c0+nl, CO-1);           // clamp pad cols; masked at store

  const float* Wn = net ? cw : aw;             // [3][F_IN][CO]

  __shared__ __align__(16) float Af[2][ABUF];  // 32 KB
  __shared__ __align__(16) float Bf[2][BBUF];  // 45 KB   (total 77 KB -> 2 blk/CU)

  v4f acc[3][7];
  #pragma unroll
  for(int g=0;g<3;++g)
    #pragma unroll
    for(int i=0;i<7;++i){ v4f z={0.f,0.f,0.f,0.f}; acc[g][i]=z; }

  // ---- staging (all waves participate; dest bases wave-uniform) ----
  auto stage = [&](float* Afb, float* Bfb, int kb){
    // A: 16 x 16B-insts; inst j covers LDS bytes [j*1024, +1024).
    // window w16 = j*64+lane -> row = w16/9 (144-B rows), u = w16%9
    // (u<8: floats u*4..u*4+3 of the row; u==8: pad slot, duplicate source).
    #pragma unroll
    for(int p=0;p<4;++p){
      int j   = wave*4 + p;
      int w16 = j*64 + lane;
      int row = w16/9, u = w16 - row*9;
      int rc  = min(row, NN-1);
      int uo  = (u==8) ? 0 : u*4;
      gl16(x + (size_t)rc*F_IN + kb + uo, Afb + j*256);
    }
    // B: per g: 7 x 16B (256 floats each) + 2 x 4B (64 floats each) = 1920 fl.
    #pragma unroll
    for(int p=0;p<7;++p){
      int idx = p*4 + wave;
      if(idx < 27){
        int g = idx/9, t = idx - g*9;
        const float* WgK = Wn + (size_t)g*F_IN*CO + (size_t)kb*CO;
        float* dg = Bfb + g*1920;
        if(t < 7) gl16(WgK + t*256 + lane*4, dg + t*256);
        else      gl4 (WgK + 1792 + (t-7)*64 + lane, dg + 1792 + (t-7)*64);
      }
    }
  };

  int cur = 0;
  stage(Af[0], Bf[0], k0);
  asm volatile("s_waitcnt vmcnt(0)" ::: "memory");
  __syncthreads();

  for(int it=0; it<NIT; ++it){
    if(it+1 < NIT)
      stage(Af[cur^1], Bf[cur^1], k0 + (it+1)*BK);     // async, in flight behind compute

    const float* Afl = Af[cur];
    const float* Bfl = Bf[cur];

    // --- B fragments: 8 strided f32 reads per g + cvt_pk ---
    v8s fB[3];
    #pragma unroll
    for(int g=0;g<3;++g){
      float b0 = Bfl[g*1920 + (quad*8+0)*60 + ccl];
      float b1 = Bfl[g*1920 + (quad*8+1)*60 + ccl];
      float b2 = Bfl[g*1920 + (quad*8+2)*60 + ccl];
      float b3 = Bfl[g*1920 + (quad*8+3)*60 + ccl];
      float b4 = Bfl[g*1920 + (quad*8+4)*60 + ccl];
      float b5 = Bfl[g*1920 + (quad*8+5)*60 + ccl];
      float b6 = Bfl[g*1920 + (quad*8+6)*60 + ccl];
      float b7 = Bfl[g*1920 + (quad*8+7)*60 + ccl];
      U8 ub;
      cvtpk(ub.u[0], b0, b1); cvtpk(ub.u[1], b2, b3);
      cvtpk(ub.u[2], b4, b5); cvtpk(ub.u[3], b6, b7);
      fB[g] = ub.s;
    }
    // --- A fragments + MFMA (A frag read once, used by all 3 matrices) ---
    #pragma unroll
    for(int mt=0; mt<7; ++mt){
      const float* ap = Afl + (mt*16+nl)*36 + quad*8;
      float4 alo = *(const float4*)(ap);
      float4 ahi = *(const float4*)(ap+4);
      U8 ua;
      cvtpk(ua.u[0], alo.x, alo.y); cvtpk(ua.u[1], alo.z, alo.w);
      cvtpk(ua.u[2], ahi.x, ahi.y); cvtpk(ua.u[3], ahi.z, ahi.w);
      #pragma unroll
      for(int g=0;g<3;++g)
        acc[g][mt] = mfma16(ua.s, fB[g], acc[g][mt]);
    }

    if(it+1 < NIT){
      asm volatile("s_waitcnt vmcnt(0)" ::: "memory");  // next tile landed
      __syncthreads();                                   // all waves done with cur
      cur ^= 1;
    }
  }

  // --- epilogue.  C/D layout: col=lane&15, row=quad*4+i ---
  const int c = c0 + nl;
  if(c < CO){
    #pragma unroll
    for(int g=0;g<3;++g){
      if(partial){
        float* pd = dst + ((size_t)(net*3+g)*G2 + s)*(NN*CO);
        #pragma unroll
        for(int mt=0;mt<7;++mt){
          #pragma unroll
          for(int i=0;i<4;++i){
            int m = mt*16 + quad*4 + i;
            if(m < NN) pd[m*CO + c] = acc[g][mt][i];
          }
        }
      } else {
        float* pd = dst + (size_t)(net*3+g)*(NN*CO);
        #pragma unroll
        for(int mt=0;mt<7;++mt){
          #pragma unroll
          for(int i=0;i<4;++i){
            int m = mt*16 + quad*4 + i;
            if(m < NN) atomicAdd(pd + m*CO + c, acc[g][mt][i]);
          }
        }
      }
    }
  }
}

// ---------------------------------------------------------------------------
// K1b: split-K reduce.  grid=(141,16): block (b,sg) sums 16 slices of P into Y
// via one atomicAdd (Y zeroed by memset).
// ---------------------------------------------------------------------------
__global__ void k_reduce(const float* __restrict__ P, float* __restrict__ Y){
  int o = blockIdx.x*256 + threadIdx.x;
  if(o >= 6*NN*CO) return;
  int gg = o/(NN*CO), r = o - gg*(NN*CO);
  const float* p = P + (size_t)gg*G2*(NN*CO) + (size_t)blockIdx.y*16*(NN*CO) + r;
  float a0=0.f,a1=0.f,a2=0.f,a3=0.f;
  #pragma unroll
  for(int s4=0;s4<16;s4+=4){
    a0 += p[(size_t)(s4  )*(NN*CO)];
    a1 += p[(size_t)(s4+1)*(NN*CO)];
    a2 += p[(size_t)(s4+2)*(NN*CO)];
    a3 += p[(size_t)(s4+3)*(NN*CO)];
  }
  atomicAdd(&Y[o], (a0+a1)+(a2+a3));
}

// ---------------------------------------------------------------------------
// K2: cheb combine.  out = Y0 - Y2 + L@(Y1 + 2*L@Y2) + b, then tanh.
// ---------------------------------------------------------------------------
__global__ void k_cheb(const float* __restrict__ Y, const int* __restrict__ ei,
                       const float* __restrict__ ab, const float* __restrict__ cb,
                       float* __restrict__ emb, float* __restrict__ out){
  const int net = blockIdx.x / CO;
  const int c   = blockIdx.x % CO;
  const int t   = threadIdx.x;       // 128
  __shared__ float L[NN][NN+1];      // stride 101: 2-way bank alias only
  __shared__ float dis[NN];
  __shared__ int   deg[NN];
  __shared__ float y0[NN], y1[NN], y2[NN], zu[NN];

  if(blockIdx.x==0 && t<101) out[t] = 0.f;

  for(int i=t;i<NN*(NN+1);i+=128) ((float*)L)[i]=0.f;
  if(t<NN) deg[t]=0;
  __syncthreads();
  for(int e=t;e<2000;e+=128) atomicAdd(&deg[ei[e]],1);
  __syncthreads();
  if(t<NN) dis[t] = deg[t]>0 ? rsqrtf((float)deg[t]) : 0.f;
  __syncthreads();
  for(int e=t;e<2000;e+=128){
    int ss = ei[e], d = ei[2000+e];
    atomicAdd(&L[d][ss], -dis[ss]*dis[d]);
  }
  if(t<NN){
    const float* yb = Y + (size_t)net*3*NN*CO + t*CO + c;
    y0[t]=yb[0]; y1[t]=yb[NN*CO]; y2[t]=yb[2*NN*CO];
  }
  __syncthreads();
  if(t<NN){
    float sv=0.f;
    #pragma unroll 4
    for(int j=0;j<NN;++j) sv += L[t][j]*y2[j];
    zu[t] = y1[t] + 2.f*sv;
  }
  __syncthreads();
  if(t<NN){
    float sv=0.f;
    #pragma unroll 4
    for(int j=0;j<NN;++j) sv += L[t][j]*zu[j];
    float b = (net==0) ? ab[c] : cb[c];
    emb[net*NN*CO + t*CO + c] = tanhf(y0[t] - y2[t] + sv + b);
  }
}

// ---------------------------------------------------------------------------
// K3: final FC.  out zeroed by k_cheb block 0.
// ---------------------------------------------------------------------------
#define FCB 50
__global__ void k_fc(const float* __restrict__ emb, const float* __restrict__ afw,
                     const float* __restrict__ afb, const float* __restrict__ cfw,
                     const float* __restrict__ cfb, const float* __restrict__ s0,
                     const float* __restrict__ s1, const float* __restrict__ s2,
                     float* __restrict__ out){
  const int b = blockIdx.x;
  const int t = threadIdx.x;         // 256
  if(b < FCB){
    const int jj = t & 127, half = t >> 7;
    if(jj < 100){
      const int i0 = b*120 + half*60;
      const float* w = afw + (size_t)i0*100 + jj;
      const float* e = emb + i0;
      float p0=0.f,p1=0.f,p2=0.f,p3=0.f;
      #pragma unroll 3
      for(int i=0;i<60;i+=4){
        p0 += e[i  ]*w[(size_t)(i  )*100];
        p1 += e[i+1]*w[(size_t)(i+1)*100];
        p2 += e[i+2]*w[(size_t)(i+2)*100];
        p3 += e[i+3]*w[(size_t)(i+3)*100];
      }
      atomicAdd(&out[jj], (p0+p1)+(p2+p3));
    }
  } else {
    float p = 0.f;
    const float* e = emb + 6000;
    for(int i=t;i<6000;i+=256) p += e[i]*cfw[i];
    #pragma unroll
    for(int o=32;o>0;o>>=1) p += __shfl_down(p,o,64);
    __shared__ float red[4];
    if((t&63)==0) red[t>>6]=p;
    __syncthreads();
    if(t==0){
      float tot = red[0]+red[1]+red[2]+red[3];
      out[100] = tot + s0[0]*cfw[6000] + s1[0]*cfw[6001] + s2[0]*cfw[6002] + cfb[0];
    }
    if(t<100){
      atomicAdd(&out[t], afb[t] + s0[0]*afw[600000+t] + s1[0]*afw[600100+t] + s2[0]*afw[600200+t]);
    }
  }
}

extern "C" void kernel_launch(void* const* d_in, const int* in_sizes, int n_in,
                              void* d_out, int out_size, void* d_ws, size_t ws_size,
                              hipStream_t stream){
  const float* x   = (const float*)d_in[0];
  const int*   ei  = (const int*)d_in[1];
  const float* s0  = (const float*)d_in[2];
  const float* s1  = (const float*)d_in[3];
  const float* s2  = (const float*)d_in[4];
  const float* aw  = (const float*)d_in[5];
  const float* ab  = (const float*)d_in[6];
  const float* cw  = (const float*)d_in[7];
  const float* cb  = (const float*)d_in[8];
  const float* afw = (const float*)d_in[9];
  const float* afb = (const float*)d_in[10];
  const float* cfw = (const float*)d_in[11];
  const float* cfb = (const float*)d_in[12];
  float* out = (float*)d_out;

  float* Y   = (float*)d_ws;                       // [6][6000] reduced GEMM outputs
  float* emb = Y + 6*NN*CO;                        // [2][6000] tanh embeddings
  float* P   = emb + 2*NN*CO;                      // [6][G2][6000] split-K partials
  const size_t need = (size_t)(6*NN*CO + 2*NN*CO)*4 + (size_t)6*G2*NN*CO*4;
  const int partial = (ws_size >= need) ? 1 : 0;

  hipMemsetAsync(Y, 0, 6*NN*CO*sizeof(float), stream);

  if(partial){
    k_gemm<<<dim3(512), 256, 0, stream>>>(x, aw, cw, P, 1);
    k_reduce<<<dim3((6*NN*CO+255)/256, 16), 256, 0, stream>>>(P, Y);
  } else {
    k_gemm<<<dim3(512), 256, 0, stream>>>(x, aw, cw, Y, 0);
  }
  k_cheb<<<120, 128, 0, stream>>>(Y, ei, ab, cb, emb, out);
  k_fc<<<FCB+1, 256, 0, stream>>>(emb, afw, afb, cfw, cfb, s0, s1, s2, out);
}